// Round 8
// baseline (4987.847 us; speedup 1.0000x reference)
//
#include <hip/hip_runtime.h>
#include <math.h>

#define TT   128
#define BSZ  256
#define IDIM 256
#define CDIM 512
#define NN   128
#define MM   64
#define GJ   2048
#define ODIM 576
#define OC   268
#define NKB1 26
#define NBLK 256

// fragment array sizes (ushort counts)
#define NXF  8388608u    // 128 t * 8 grp * 8 kb * 2 half * 64 lane * 8 e
#define NHFB 131072u     // per buffer: 8 grp * 16 kb * 2 half * 64 * 8
#define NRFB 16384u      // per buffer: 8 grp * 2 kb * 2 half * 64 * 8

typedef __attribute__((ext_vector_type(8))) short s16x8;
typedef __attribute__((ext_vector_type(4))) float f32x4;
typedef unsigned short ush;
#define MFMA __builtin_amdgcn_mfma_f32_16x16x32_bf16

__device__ __forceinline__ float sigmoidf_(float x) { return 1.0f / (1.0f + expf(-x)); }
__device__ __forceinline__ float softplusf_(float x) {
    return (x > 0.f) ? (x + log1pf(expf(-x))) : log1pf(expf(x));
}
__device__ __forceinline__ ush f2bf(float f) {
    unsigned int u = __builtin_bit_cast(unsigned int, f);
    u += 0x7FFFu + ((u >> 16) & 1u);
    return (ush)(u >> 16);
}
__device__ __forceinline__ float bf2f(ush b) {
    unsigned int u = ((unsigned int)b) << 16;
    return __builtin_bit_cast(float, u);
}
__device__ __forceinline__ void split2(float v, ush& h, ush& lo) {
    h = f2bf(v);
    lo = f2bf(v - bf2f(h));
}

// ---- IC-coherent accesses (cross-XCD), split issue/drain ----
__device__ __forceinline__ void load4_sc_async(const void* p, f32x4& a) {
    asm volatile("global_load_dwordx4 %0, %1, off sc0 sc1" : "=&v"(a) : "v"(p));
}
__device__ __forceinline__ void store1_sc(float* p, float v) {
    asm volatile("global_store_dword %0, %1, off sc0 sc1" :: "v"(p), "v"(v) : "memory");
}
__device__ __forceinline__ void store2_sc(ush* p, ush v) {
    unsigned int vv = v;
    asm volatile("global_store_short %0, %1, off sc0 sc1" :: "v"(p), "v"(vv) : "memory");
}
#define DRAIN() do { asm volatile("s_waitcnt vmcnt(0)" ::: "memory"); __builtin_amdgcn_sched_barrier(0); } while (0)

__device__ __forceinline__ void spin_ge(unsigned* p, unsigned tgt) {
    while (__hip_atomic_load(p, __ATOMIC_RELAXED, __HIP_MEMORY_SCOPE_AGENT) < tgt)
        __builtin_amdgcn_s_sleep(2);
    __builtin_amdgcn_sched_barrier(0);
}
__device__ __forceinline__ void inc_cnt(unsigned* p) {
    __hip_atomic_fetch_add(p, 1u, __ATOMIC_RELAXED, __HIP_MEMORY_SCOPE_AGENT);
}

// ---------------- prep: pack gates weights (fragment order, split hi/lo) ----------------
__global__ void k_packB1(const float* __restrict__ W_ih, const float* __restrict__ W_hh,
                         const float* __restrict__ b_ih, const float* __restrict__ b_hh,
                         ush* __restrict__ Bh, ush* __restrict__ Bl, float* __restrict__ bias)
{
    const int total = NKB1 * 32 * 4 * 64 * 8;
    for (int idx = blockIdx.x * 256 + threadIdx.x; idx < total + GJ; idx += gridDim.x * 256) {
        if (idx < total) {
            int e  = idx & 7;
            int l  = (idx >> 3) & 63;
            int g  = (idx >> 9) & 3;
            int jt = (idx >> 11) & 31;
            int kb = idx >> 16;
            int k  = kb * 32 + ((l >> 4) << 3) + e;
            int n  = g * 512 + jt * 16 + (l & 15);
            float v = (k < 320) ? W_ih[n * 320 + k] : W_hh[n * 512 + (k - 320)];
            ush h_, l_;
            split2(v, h_, l_);
            Bh[idx] = h_; Bl[idx] = l_;
        } else {
            int j = idx - total;
            bias[j] = b_ih[j] + b_hh[j];
        }
    }
}

// ---------------- prep: x -> fragments for all t ----------------
__global__ void k_packXF(const float* __restrict__ inp, ush* __restrict__ XFh, ush* __restrict__ XFl)
{
    for (unsigned idx = blockIdx.x * 256 + threadIdx.x; idx < NXF; idx += gridDim.x * 256) {
        int e    = idx & 7;
        int lane = (idx >> 3) & 63;
        int half = (idx >> 9) & 1;
        int kb   = (idx >> 10) & 7;
        int grp  = (idx >> 13) & 7;
        int t    = idx >> 16;
        int b = grp * 32 + half * 16 + (lane & 15);
        int k = kb * 32 + ((lane >> 4) << 3) + e;
        float v = inp[((size_t)t * BSZ + b) * IDIM + k];
        ush h_, l_;
        split2(v, h_, l_);
        XFh[idx] = h_; XFl[idx] = l_;
    }
}

// ---------------- prep: initial h/rdv fragments (buffer 0) ----------------
__global__ void k_packInit(const float* __restrict__ hid, const float* __restrict__ r0,
                           ush* __restrict__ HFh, ush* __restrict__ HFl,
                           ush* __restrict__ RFh, ush* __restrict__ RFl)
{
    const unsigned tot = NHFB + NRFB;
    for (unsigned idx = blockIdx.x * 256 + threadIdx.x; idx < tot; idx += gridDim.x * 256) {
        if (idx < NHFB) {
            int e    = idx & 7;
            int lane = (idx >> 3) & 63;
            int half = (idx >> 9) & 1;
            int kb   = (idx >> 10) & 15;
            int grp  = idx >> 14;
            int b = grp * 32 + half * 16 + (lane & 15);
            int k = kb * 32 + ((lane >> 4) << 3) + e;
            float v = hid[b * CDIM + k];
            ush h_, l_;
            split2(v, h_, l_);
            HFh[idx] = h_; HFl[idx] = l_;
        } else {
            unsigned j = idx - NHFB;
            int e    = j & 7;
            int lane = (j >> 3) & 63;
            int kb   = (j >> 10) & 1;
            float v = r0[kb * 32 + ((lane >> 4) << 3) + e];
            ush h_, l_;
            split2(v, h_, l_);
            RFh[j] = h_; RFl[j] = l_;
        }
    }
}

// ---------------- prep: heads weights W2T[272][512] fp32 ----------------
__global__ void k_packW2(const float* __restrict__ rW, const float* __restrict__ rb,
                         const float* __restrict__ wW, const float* __restrict__ wb,
                         float* __restrict__ W2T, float* __restrict__ bias2)
{
    const int total = 272 * 512;
    for (int idx = blockIdx.x * 256 + threadIdx.x; idx < total + 272; idx += gridDim.x * 256) {
        if (idx < total) {
            int j = idx >> 9, k = idx & 511;
            float v = 0.f;
            if (j < 70)      v = rW[k * 70 + j];
            else if (j < OC) v = wW[k * 198 + (j - 70)];
            W2T[idx] = v;
        } else {
            int j = idx - total;
            bias2[j] = (j < 70) ? rb[j] : ((j < OC) ? wb[j - 70] : 0.f);
        }
    }
}

__global__ void k_barinit(unsigned* __restrict__ bar) {
    for (int i = threadIdx.x; i < 1024; i += 64) bar[i] = 0u;
}

// ---------------- persistent dataflow kernel ----------------
__global__ __launch_bounds__(256, 1) void k_persist(
    const ush* __restrict__ XFh, const ush* __restrict__ XFl,
    const ush* __restrict__ B1h, const ush* __restrict__ B1l, const float* __restrict__ bias1,
    ush* __restrict__ HFh, ush* __restrict__ HFl,
    ush* __restrict__ RFh, ush* __restrict__ RFl,
    const float* __restrict__ W2T, const float* __restrict__ bias2,
    const float* __restrict__ c0, const float* __restrict__ mem_bias,
    float* __restrict__ h0, float* __restrict__ h1,
    float* __restrict__ out, unsigned* __restrict__ bar)
{
    __shared__ __align__(16) char scratch[16384];   // A: red0|red1 ; B: hs
    __shared__ float ms[NN * 65];
    __shared__ float os_l[272];
    __shared__ float wr_s[NN], ww_s[NN], wgs[NN], wsh[NN];
    __shared__ float red4[4];
    __shared__ float esh[MM], ash[MM];

    float* red0 = (float*)scratch;
    float* red1 = (float*)(scratch + 8192);
    float* hs   = (float*)scratch;

    const int bid = blockIdx.x;
    const int tid = threadIdx.x;
    const int wid = tid >> 6, l = tid & 63;
    const int rr = l & 15;

    const int grp = bid >> 5;
    const int jt  = bid & 31;
    const int m0  = grp * 32;
    const int b   = bid;

    unsigned* cntA = bar + grp * 32;
    unsigned* cntB = bar + 512 + grp * 32;

    // ---- per-block persistent state ----
    for (int i = tid; i < NN * MM; i += 256) {
        int n = i >> 6, m = i & 63;
        ms[n * 65 + m] = mem_bias[i];
    }
    if (tid < NN) { wr_s[tid] = 0.f; ww_s[tid] = 0.f; }

    float c_reg[2][4];
    float bjv[4];
    {
        int jg = jt * 16 + rr;
#pragma unroll
        for (int s = 0; s < 2; ++s)
#pragma unroll
            for (int r = 0; r < 4; ++r) c_reg[s][r] = c0[jg];
        bjv[0] = bias1[jg];        bjv[1] = bias1[512 + jg];
        bjv[2] = bias1[1024 + jg]; bjv[3] = bias1[1536 + jg];
    }
    __syncthreads();

    for (int t = 0; t < TT; ++t) {
        float* hout  = (t & 1) ? h0 : h1;
        float* out_t = out + (size_t)t * BSZ * ODIM;

        // ================= phase A: gates GEMM (fragments) + LSTM =================
        {
            // pre-issue this wave's 4 h-kb fragment loads (sc, IC)
            const ush* HFhB = HFh + (size_t)(t & 1) * NHFB + (size_t)grp * 16384;
            const ush* HFlB = HFl + (size_t)(t & 1) * NHFB + (size_t)grp * 16384;
            f32x4 ph[4][4];
#pragma unroll
            for (int i = 0; i < 4; ++i) {
                const int kh = wid + 4 * i;            // local h kb 0..15
                const size_t o0 = (size_t)(kh * 2 + 0) * 512 + l * 8;
                const size_t o1 = (size_t)(kh * 2 + 1) * 512 + l * 8;
                load4_sc_async(HFhB + o0, ph[i][0]);
                load4_sc_async(HFlB + o0, ph[i][1]);
                load4_sc_async(HFhB + o1, ph[i][2]);
                load4_sc_async(HFlB + o1, ph[i][3]);
            }

            f32x4 acc[2][4];
#pragma unroll
            for (int s = 0; s < 2; ++s)
#pragma unroll
                for (int g = 0; g < 4; ++g) acc[s][g] = (f32x4){0.f, 0.f, 0.f, 0.f};

#define PROC_FRAG(KB, A0H, A0L, A1H, A1L)                                       \
            {                                                                   \
                const int boff = (((KB) * 32 + jt) * 256 + l) * 8;              \
                s16x8 bfh[4], bfl[4];                                           \
                _Pragma("unroll")                                               \
                for (int g = 0; g < 4; ++g) {                                   \
                    bfh[g] = *(const s16x8*)(B1h + boff + g * 512);             \
                    bfl[g] = *(const s16x8*)(B1l + boff + g * 512);             \
                }                                                               \
                _Pragma("unroll")                                               \
                for (int g = 0; g < 4; ++g) {                                   \
                    acc[0][g] = MFMA((A0H), bfh[g], acc[0][g], 0, 0, 0);        \
                    acc[1][g] = MFMA((A1H), bfh[g], acc[1][g], 0, 0, 0);        \
                    acc[0][g] = MFMA((A0L), bfh[g], acc[0][g], 0, 0, 0);        \
                    acc[1][g] = MFMA((A1L), bfh[g], acc[1][g], 0, 0, 0);        \
                    acc[0][g] = MFMA((A0H), bfl[g], acc[0][g], 0, 0, 0);        \
                    acc[1][g] = MFMA((A1H), bfl[g], acc[1][g], 0, 0, 0);        \
                }                                                               \
            }

            // x-kbs: direct fragment loads (normal cached)
            const size_t xbase = (((size_t)t * 8 + grp) * 8) * 1024;
#pragma unroll
            for (int i = 0; i < 2; ++i) {
                const int kb = wid + 4 * i;            // global kb 0..7
                const ush* xh = XFh + xbase + (size_t)kb * 1024 + l * 8;
                const ush* xl = XFl + xbase + (size_t)kb * 1024 + l * 8;
                s16x8 a0h = *(const s16x8*)xh;
                s16x8 a0l = *(const s16x8*)xl;
                s16x8 a1h = *(const s16x8*)(xh + 512);
                s16x8 a1l = *(const s16x8*)(xl + 512);
                PROC_FRAG(kb, a0h, a0l, a1h, a1l);
            }

            DRAIN();   // h fragments arrived
#pragma unroll
            for (int i = 0; i < 4; ++i) {
                const int kb = 10 + wid + 4 * i;       // global kb 10..25
                s16x8 a0h = __builtin_bit_cast(s16x8, ph[i][0]);
                s16x8 a0l = __builtin_bit_cast(s16x8, ph[i][1]);
                s16x8 a1h = __builtin_bit_cast(s16x8, ph[i][2]);
                s16x8 a1l = __builtin_bit_cast(s16x8, ph[i][3]);
                PROC_FRAG(kb, a0h, a0l, a1h, a1l);
            }

            // rdv-kb last (waves 0,1)
            if (wid < 2) {
                if (t > 0) spin_ge(cntA, 32u * t);
                const ush* RFhB = RFh + (size_t)(t & 1) * NRFB + (size_t)grp * 2048;
                const ush* RFlB = RFl + (size_t)(t & 1) * NRFB + (size_t)grp * 2048;
                const size_t o0 = (size_t)(wid * 2 + 0) * 512 + l * 8;
                const size_t o1 = (size_t)(wid * 2 + 1) * 512 + l * 8;
                f32x4 q0, q1, q2, q3;
                load4_sc_async(RFhB + o0, q0);
                load4_sc_async(RFlB + o0, q1);
                load4_sc_async(RFhB + o1, q2);
                load4_sc_async(RFlB + o1, q3);
                DRAIN();
                s16x8 a0h = __builtin_bit_cast(s16x8, q0);
                s16x8 a0l = __builtin_bit_cast(s16x8, q1);
                s16x8 a1h = __builtin_bit_cast(s16x8, q2);
                s16x8 a1l = __builtin_bit_cast(s16x8, q3);
                PROC_FRAG(8 + wid, a0h, a0l, a1h, a1l);
            }
#undef PROC_FRAG

            // split-K reduce: (0+=2),(1+=3),(0+=1); epilogue on wave 0
            __syncthreads();
            if (wid >= 2) {
                float* dst = (wid == 2) ? red0 : red1;
#pragma unroll
                for (int s = 0; s < 2; ++s)
#pragma unroll
                    for (int g = 0; g < 4; ++g)
#pragma unroll
                        for (int r = 0; r < 4; ++r)
                            dst[((s * 16 + (l >> 4) * 4 + r) << 6) + (g << 4) + rr] = acc[s][g][r];
            }
            __syncthreads();
            if (wid < 2) {
                const float* src = (wid == 0) ? red0 : red1;
#pragma unroll
                for (int s = 0; s < 2; ++s)
#pragma unroll
                    for (int g = 0; g < 4; ++g)
#pragma unroll
                        for (int r = 0; r < 4; ++r)
                            acc[s][g][r] += src[((s * 16 + (l >> 4) * 4 + r) << 6) + (g << 4) + rr];
            }
            __syncthreads();
            if (wid == 1) {
#pragma unroll
                for (int s = 0; s < 2; ++s)
#pragma unroll
                    for (int g = 0; g < 4; ++g)
#pragma unroll
                        for (int r = 0; r < 4; ++r)
                            red0[((s * 16 + (l >> 4) * 4 + r) << 6) + (g << 4) + rr] = acc[s][g][r];
            }
            __syncthreads();
            if (wid == 0) {
                const int jg  = jt * 16 + rr;
                const int kbh = jg >> 5;
                const int kk  = jg & 31;
                const int eh  = kk & 7;
                const int lq  = (kk >> 3) << 4;
                ush* HFhN = HFh + (size_t)((t + 1) & 1) * NHFB + (size_t)grp * 16384;
                ush* HFlN = HFl + (size_t)((t + 1) & 1) * NHFB + (size_t)grp * 16384;
#pragma unroll
                for (int s = 0; s < 2; ++s)
#pragma unroll
                    for (int r = 0; r < 4; ++r) {
                        const int row = s * 16 + (l >> 4) * 4 + r;
                        const int ridx = (row << 6) + rr;
                        float gi  = acc[s][0][r] + red0[ridx]       + bjv[0];
                        float gf  = acc[s][1][r] + red0[ridx + 16]  + bjv[1];
                        float gg2 = acc[s][2][r] + red0[ridx + 32]  + bjv[2];
                        float go  = acc[s][3][r] + red0[ridx + 48]  + bjv[3];
                        float cn = sigmoidf_(gf) * c_reg[s][r] + sigmoidf_(gi) * tanhf(gg2);
                        float hn = sigmoidf_(go) * tanhf(cn);
                        c_reg[s][r] = cn;
                        const int b2 = m0 + row;
                        out_t[b2 * ODIM + jg] = hn;
                        store1_sc(&hout[b2 * CDIM + jg], hn);
                        ush hi_, lo_;
                        split2(hn, hi_, lo_);
                        const int lane_ = ((l >> 4) * 4 + r) + lq;
                        const size_t fo = (size_t)(kbh * 2 + s) * 512 + lane_ * 8 + eh;
                        store2_sc(HFhN + fo, hi_);
                        store2_sc(HFlN + fo, lo_);
                    }
                DRAIN();
            }
            __syncthreads();
            if (tid == 0) inc_cnt(cntB);
        }

        // ================= phase B: heads (direct) + addressing + memory update =================
        {
            spin_ge(cntB, 32u * (t + 1));

            // h row for this batch element
            if (tid < 128) {
                f32x4 hv;
                load4_sc_async(&hout[b * CDIM + tid * 4], hv);
                DRAIN();
                *(f32x4*)&hs[tid * 4] = hv;
            }
            __syncthreads();

            // o[j] = bias2[j] + W2T[j] . h
            {
                float a0 = bias2[tid];
                const f32x4* wr = (const f32x4*)(W2T + tid * 512);
                float av = 0.f;
#pragma unroll 8
                for (int k4 = 0; k4 < 128; ++k4) {
                    f32x4 w = wr[k4];
                    av += hs[k4 * 4 + 0] * w.x + hs[k4 * 4 + 1] * w.y
                        + hs[k4 * 4 + 2] * w.z + hs[k4 * 4 + 3] * w.w;
                }
                os_l[tid] = a0 + av;
                if (tid < 16) {
                    const int j2 = 256 + tid;
                    float a1 = bias2[j2];
                    const f32x4* wr2 = (const f32x4*)(W2T + j2 * 512);
                    float av2 = 0.f;
#pragma unroll 8
                    for (int k4 = 0; k4 < 128; ++k4) {
                        f32x4 w = wr2[k4];
                        av2 += hs[k4 * 4 + 0] * w.x + hs[k4 * 4 + 1] * w.y
                             + hs[k4 * 4 + 2] * w.z + hs[k4 * 4 + 3] * w.w;
                    }
                    os_l[j2] = a1 + av2;
                }
            }
            __syncthreads();

            for (int head = 0; head < 2; ++head) {
                const int ob = head ? 70 : 0;
                float* wst = head ? ww_s : wr_s;

                float beta = softplusf_(os_l[ob + 64]);
                float gte  = sigmoidf_(os_l[ob + 65]);
                float s0r = os_l[ob + 66], s1r = os_l[ob + 67], s2r = os_l[ob + 68];
                float smx = fmaxf(s0r, fmaxf(s1r, s2r));
                float e0 = expf(s0r - smx), e1 = expf(s1r - smx), e2 = expf(s2r - smx);
                float einv = 1.f / (e0 + e1 + e2);
                float s0 = e0 * einv, s1 = e1 * einv, s2 = e2 * einv;
                float gamma = 1.f + softplusf_(os_l[ob + 69]);

                float simv = -1e30f;
                if (tid < NN) {
                    float dot = 0.f, nm2 = 0.f, nk2 = 0.f;
                    const float* mrow = ms + tid * 65;
#pragma unroll 8
                    for (int m = 0; m < MM; ++m) {
                        float mv = mrow[m] + 1e-16f;
                        float kv = os_l[ob + m] + 1e-16f;
                        dot += mv * kv; nm2 += mv * mv; nk2 += kv * kv;
                    }
                    float nm = fmaxf(sqrtf(nm2), 1e-8f);
                    float nk = fmaxf(sqrtf(nk2), 1e-8f);
                    simv = beta * dot / (nm * nk);
                }
                float v = simv;
#pragma unroll
                for (int off = 32; off; off >>= 1) v = fmaxf(v, __shfl_xor(v, off));
                if ((tid & 63) == 0) red4[tid >> 6] = v;
                __syncthreads();
                float smax = fmaxf(fmaxf(red4[0], red4[1]), fmaxf(red4[2], red4[3]));
                __syncthreads();

                float pv = (tid < NN) ? expf(simv - smax) : 0.f;
                v = pv;
#pragma unroll
                for (int off = 32; off; off >>= 1) v += __shfl_xor(v, off);
                if ((tid & 63) == 0) red4[tid >> 6] = v;
                __syncthreads();
                float psum = red4[0] + red4[1] + red4[2] + red4[3];
                __syncthreads();

                if (tid < NN) {
                    float wc = pv / psum;
                    wgs[tid] = gte * wc + (1.f - gte) * wst[tid];
                }
                __syncthreads();

                float wv_ = 0.f;
                if (tid < NN) {
                    int nl = (tid + NN - 1) & (NN - 1), nr = (tid + 1) & (NN - 1);
                    float wwv = s0 * wgs[nl] + s1 * wgs[tid] + s2 * wgs[nr];
                    wv_ = powf(wwv, gamma);
                }
                v = wv_;
#pragma unroll
                for (int off = 32; off; off >>= 1) v += __shfl_xor(v, off);
                if ((tid & 63) == 0) red4[tid >> 6] = v;
                __syncthreads();
                float wsum = red4[0] + red4[1] + red4[2] + red4[3];
                __syncthreads();

                if (tid < NN) {
                    float wfin = wv_ / (wsum + 1e-16f);
                    wsh[tid] = wfin;
                    wst[tid] = wfin;
                }
                __syncthreads();

                if (head == 0) {
                    // read vector -> out + rdv fragments for A(t+1)
                    if (tid < MM) {
                        float r = 0.f;
#pragma unroll 8
                        for (int n = 0; n < NN; ++n) r += wsh[n] * ms[n * 65 + tid];
                        out_t[b * ODIM + CDIM + tid] = r;
                        ush hi_, lo_;
                        split2(r, hi_, lo_);
                        const int row = b & 31;
                        const int kbr = tid >> 5, kk = tid & 31;
                        const int lane_ = (row & 15) + ((kk >> 3) << 4);
                        const size_t fo = (size_t)((t + 1) & 1) * NRFB + (size_t)grp * 2048
                                        + (size_t)(kbr * 2 + (row >> 4)) * 512 + lane_ * 8 + (kk & 7);
                        store2_sc(RFh + fo, hi_);
                        store2_sc(RFl + fo, lo_);
                    }
                    if (wid == 0) DRAIN();
                    __syncthreads();
                    if (tid == 0) inc_cnt(cntA);
                } else {
                    if (tid < MM) {
                        esh[tid] = sigmoidf_(os_l[140 + tid]);
                        ash[tid] = os_l[204 + tid];
                    }
                    __syncthreads();
                    for (int i = tid; i < NN * MM / 4; i += 256) {
                        int n = i >> 4, m4 = (i & 15) * 4;
                        float wvn = wsh[n];
#pragma unroll
                        for (int q = 0; q < 4; ++q) {
                            float mv = ms[n * 65 + m4 + q];
                            ms[n * 65 + m4 + q] = mv * (1.f - wvn * esh[m4 + q]) + wvn * ash[m4 + q];
                        }
                    }
                    __syncthreads();
                }
            }
        }
    }
}

extern "C" void kernel_launch(void* const* d_in, const int* in_sizes, int n_in,
                              void* d_out, int out_size, void* d_ws, size_t ws_size,
                              hipStream_t stream) {
    const float* inp      = (const float*)d_in[0];
    const float* hid      = (const float*)d_in[1];
    const float* c0       = (const float*)d_in[2];
    const float* mem_bias = (const float*)d_in[3];
    const float* r0       = (const float*)d_in[4];
    const float* W_ih     = (const float*)d_in[5];
    const float* W_hh     = (const float*)d_in[6];
    const float* b_ih     = (const float*)d_in[7];
    const float* b_hh     = (const float*)d_in[8];
    const float* read_W   = (const float*)d_in[9];
    const float* read_b   = (const float*)d_in[10];
    const float* write_W  = (const float*)d_in[11];
    const float* write_b  = (const float*)d_in[12];
    float* out = (float*)d_out;

    char* p = (char*)d_ws;
    auto alloc = [&](size_t bytes) { char* r = p; p += (bytes + 255) & ~(size_t)255; return r; };
    const size_t nB1 = (size_t)NKB1 * 32 * 4 * 64 * 8;
    ush* XFh = (ush*)alloc((size_t)NXF * 2);
    ush* XFl = (ush*)alloc((size_t)NXF * 2);
    ush* B1h = (ush*)alloc(nB1 * 2);
    ush* B1l = (ush*)alloc(nB1 * 2);
    ush* HFh = (ush*)alloc((size_t)2 * NHFB * 2);
    ush* HFl = (ush*)alloc((size_t)2 * NHFB * 2);
    ush* RFh = (ush*)alloc((size_t)2 * NRFB * 2);
    ush* RFl = (ush*)alloc((size_t)2 * NRFB * 2);
    float* bias1 = (float*)alloc(GJ * 4);
    float* W2T   = (float*)alloc(272 * 512 * 4);
    float* bias2 = (float*)alloc(272 * 4);
    float* h0    = (float*)alloc((size_t)BSZ * CDIM * 4);
    float* h1    = (float*)alloc((size_t)BSZ * CDIM * 4);
    unsigned* bar = (unsigned*)alloc(1024 * 4);

    k_packB1<<<2048, 256, 0, stream>>>(W_ih, W_hh, b_ih, b_hh, B1h, B1l, bias1);
    k_packXF<<<8192, 256, 0, stream>>>(inp, XFh, XFl);
    k_packInit<<<576, 256, 0, stream>>>(hid, r0, HFh, HFl, RFh, RFl);
    k_packW2<<<546, 256, 0, stream>>>(read_W, read_b, write_W, write_b, W2T, bias2);
    k_barinit<<<1, 64, 0, stream>>>(bar);

    k_persist<<<dim3(NBLK), dim3(256), 0, stream>>>(
        XFh, XFl, B1h, B1l, bias1,
        HFh, HFl, RFh, RFl,
        W2T, bias2, c0, mem_bias,
        h0, h1, out, bar);
}